// Round 1
// baseline (3838.356 us; speedup 1.0000x reference)
//
#include <hip/hip_runtime.h>
#include <math.h>

#define H 8
#define DK 16
#define C 8
#define M 4

// Monotone float->uint encoding: unsigned compare order == float order.
__device__ __forceinline__ unsigned int enc_f32(float x) {
    unsigned int u = __float_as_uint(x);
    return (u & 0x80000000u) ? ~u : (u | 0x80000000u);
}
__device__ __forceinline__ float dec_f32(unsigned int u) {
    u = (u & 0x80000000u) ? (u & 0x7FFFFFFFu) : ~u;
    return __uint_as_float(u);
}

// K0: zero feat accumulator + denom, init segmax to encoded(-inf)
__global__ void init_kernel(float* __restrict__ feat, float* __restrict__ denom,
                            unsigned int* __restrict__ segmax, int nfeat, int nnh) {
    int i = blockIdx.x * blockDim.x + threadIdx.x;
    if (i < nfeat) feat[i] = 0.0f;
    if (i < nnh) {
        denom[i] = 0.0f;
        segmax[i] = 0x007FFFFFu;  // enc_f32(-inf)
    }
}

// K1: logits[e,h] = scale * dot(key[e,h,:], query[dst[e],h,:]); atomicMax segmax
__global__ void logits_kernel(const float* __restrict__ key_e,
                              const float* __restrict__ query_n,
                              const int* __restrict__ edge_dst,
                              float* __restrict__ prelogits,
                              unsigned int* __restrict__ segmax,
                              int EH, float scale) {
    int i = blockIdx.x * blockDim.x + threadIdx.x;
    if (i >= EH) return;
    int e = i >> 3;      // / H
    int h = i & 7;       // % H
    int n = edge_dst[e];
    const float4* kp = (const float4*)(key_e + (size_t)i * DK);
    const float4* qp = (const float4*)(query_n + ((size_t)n * H + h) * DK);
    float acc = 0.0f;
#pragma unroll
    for (int j = 0; j < 4; ++j) {
        float4 k4 = kp[j];
        float4 q4 = qp[j];
        acc += k4.x * q4.x + k4.y * q4.y + k4.z * q4.z + k4.w * q4.w;
    }
    float logit = acc * scale;
    prelogits[i] = logit;
    atomicMax(segmax + (size_t)n * H + h, enc_f32(logit));
}

// K2: denom[n,h] += exp(logit - max)
__global__ void denom_kernel(const float* __restrict__ prelogits,
                             const int* __restrict__ edge_dst,
                             const unsigned int* __restrict__ segmax,
                             float* __restrict__ denom, int EH) {
    int i = blockIdx.x * blockDim.x + threadIdx.x;
    if (i >= EH) return;
    int e = i >> 3;
    int h = i & 7;
    int nh = edge_dst[e] * H + h;
    float m = dec_f32(segmax[nh]);
    float ex = __expf(prelogits[i] - m);
    atomicAdd(denom + nh, ex);
}

// K3: feat[n,h,c,:] += w[e,h] * value[e,h,c,:]   (one thread per (e,h,c))
__global__ void scatter_kernel(const float* __restrict__ value_e,
                               const float* __restrict__ prelogits,
                               const int* __restrict__ edge_dst,
                               const unsigned int* __restrict__ segmax,
                               const float* __restrict__ denom,
                               float* __restrict__ feat, int EHC) {
    int i = blockIdx.x * blockDim.x + threadIdx.x;
    if (i >= EHC) return;
    int eh = i >> 3;     // e*H + h
    int c  = i & 7;
    int e  = eh >> 3;
    int h  = eh & 7;
    int nh = edge_dst[e] * H + h;
    float m = dec_f32(segmax[nh]);
    float w = __expf(prelogits[eh] - m) / (denom[nh] + 1e-9f);
    float4 v = ((const float4*)value_e)[i];  // value_e[e,h,c,0:4], 16B coalesced
    float* dst = feat + (size_t)nh * (C * M) + c * M;
    atomicAdd(dst + 0, w * v.x);
    atomicAdd(dst + 1, w * v.y);
    atomicAdd(dst + 2, w * v.z);
    atomicAdd(dst + 3, w * v.w);
}

extern "C" void kernel_launch(void* const* d_in, const int* in_sizes, int n_in,
                              void* d_out, int out_size, void* d_ws, size_t ws_size,
                              hipStream_t stream) {
    const float* key_e   = (const float*)d_in[0];
    const float* query_n = (const float*)d_in[1];
    const float* value_e = (const float*)d_in[2];
    const int*   edge_dst = (const int*)d_in[3];

    const int E = in_sizes[3];
    const int N = in_sizes[1] / (H * DK);
    const int EH = E * H;
    const int EHC = EH * C;
    const int NH = N * H;
    const int NFEAT = N * H * C * M;

    float* out = (float*)d_out;
    float* feat = out;                           // [N,H,C,M]
    float* prelogits = out + (size_t)NFEAT;      // [E,H]

    unsigned int* segmax = (unsigned int*)d_ws;          // NH uints
    float* denom = (float*)d_ws + (size_t)NH;            // NH floats

    const float scale = 1.0f / sqrtf((float)(H * DK));

    const int B = 256;
    {
        int n = NFEAT > NH ? NFEAT : NH;
        init_kernel<<<(n + B - 1) / B, B, 0, stream>>>(feat, denom, segmax, NFEAT, NH);
    }
    logits_kernel<<<(EH + B - 1) / B, B, 0, stream>>>(key_e, query_n, edge_dst,
                                                      prelogits, segmax, EH, scale);
    denom_kernel<<<(EH + B - 1) / B, B, 0, stream>>>(prelogits, edge_dst, segmax,
                                                     denom, EH);
    scatter_kernel<<<(EHC + B - 1) / B, B, 0, stream>>>(value_e, prelogits, edge_dst,
                                                        segmax, denom, feat, EHC);
}